// Round 6
// baseline (699.117 us; speedup 1.0000x reference)
//
#include <hip/hip_runtime.h>
#include <hip/hip_bf16.h>
#include <cmath>

#define N_ENT  50000
#define N_RELS 16
#define N_EDGE 1000000
#define DIM    64
#define OUT_STRIDE 176

typedef float f32x4 __attribute__((ext_vector_type(4)));
typedef short s16x8 __attribute__((ext_vector_type(8)));

__device__ inline void bf16x8_unpack(uint4 u, float* f) {
    f[0] = __uint_as_float((u.x & 0xffffu) << 16);
    f[1] = __uint_as_float(u.x & 0xffff0000u);
    f[2] = __uint_as_float((u.y & 0xffffu) << 16);
    f[3] = __uint_as_float(u.y & 0xffff0000u);
    f[4] = __uint_as_float((u.z & 0xffffu) << 16);
    f[5] = __uint_as_float(u.z & 0xffff0000u);
    f[6] = __uint_as_float((u.w & 0xffffu) << 16);
    f[7] = __uint_as_float(u.w & 0xffff0000u);
}

// ---------------------------------------------------------------------------
// K0a: convert ent fp32 -> bf16
// ---------------------------------------------------------------------------
__global__ __launch_bounds__(256) void ent2bf16_kernel(
        const float* __restrict__ ent, ushort* __restrict__ ent_bf, int total) {
    int i = blockIdx.x * blockDim.x + threadIdx.x;
    if (i < total) {
        __hip_bfloat16 b = __float2bfloat16(ent[i]);
        ent_bf[i] = *(ushort*)&b;
    }
}

// ---------------------------------------------------------------------------
// K1: histogram of dst -> counts
// ---------------------------------------------------------------------------
__global__ __launch_bounds__(256) void hist_kernel(
        const int* __restrict__ dst, int* __restrict__ counts, int n) {
    int i = blockIdx.x * blockDim.x + threadIdx.x;
    if (i < n) atomicAdd(&counts[dst[i]], 1);
}

// ---------------------------------------------------------------------------
// K2: exclusive scan counts -> row_ptr (single block, 1024 threads)
// ---------------------------------------------------------------------------
__global__ __launch_bounds__(1024) void scan_kernel(
        const int* __restrict__ counts, int* __restrict__ row_ptr, int n) {
    __shared__ int sums[1024];
    int t = threadIdx.x;
    int chunk = (n + 1023) / 1024;
    int start = t * chunk;
    int end = start + chunk; if (end > n) end = n;
    int s = 0;
    for (int i = start; i < end && i >= 0; ++i) s += counts[i];
    sums[t] = s;
    __syncthreads();
    for (int off = 1; off < 1024; off <<= 1) {
        int v = (t >= off) ? sums[t - off] : 0;
        __syncthreads();
        sums[t] += v;
        __syncthreads();
    }
    int prefix = (t == 0) ? 0 : sums[t - 1];
    for (int i = start; i < end; ++i) {
        row_ptr[i] = prefix;
        prefix += counts[i];
    }
    if (end == n) row_ptr[n] = prefix;
}

// ---------------------------------------------------------------------------
// K3a: proj[r] = ent @ W_R[r] via bf16 MFMA (fp32 accum, bf16 store).
// ---------------------------------------------------------------------------
__global__ __launch_bounds__(256) void proj_mfma_kernel(
        const ushort* __restrict__ ent_bf,
        const float*  __restrict__ W_R,
        __hip_bfloat16* __restrict__ proj) {
    int lane = threadIdx.x & 63;
    int m    = lane & 15;
    int q    = lane >> 4;
    int r    = blockIdx.y;
    int wid  = blockIdx.x * (blockDim.x >> 6) + (threadIdx.x >> 6);
    int nw   = gridDim.x * (blockDim.x >> 6);

    const float* Wr = W_R + (size_t)r * DIM * DIM;
    s16x8 bfrag[4][2];
#pragma unroll
    for (int c = 0; c < 4; ++c)
#pragma unroll
        for (int ch = 0; ch < 2; ++ch)
#pragma unroll
            for (int j = 0; j < 8; ++j) {
                __hip_bfloat16 b = __float2bfloat16(Wr[(ch * 32 + q * 8 + j) * DIM + c * 16 + m]);
                bfrag[c][ch][j] = *(short*)&b;
            }

    __hip_bfloat16* projr = proj + (size_t)r * N_ENT * DIM;
    const int ntiles = N_ENT / 16;

    for (int t = wid; t < ntiles; t += nw) {
        int row0 = t * 16;
        const s16x8* arow = (const s16x8*)(ent_bf + (size_t)(row0 + m) * DIM);
        s16x8 a0 = arow[q];
        s16x8 a1 = arow[4 + q];
        f32x4 acc[4];
#pragma unroll
        for (int c = 0; c < 4; ++c) acc[c] = (f32x4){0.f, 0.f, 0.f, 0.f};
#pragma unroll
        for (int c = 0; c < 4; ++c) {
            acc[c] = __builtin_amdgcn_mfma_f32_16x16x32_bf16(a0, bfrag[c][0], acc[c], 0, 0, 0);
            acc[c] = __builtin_amdgcn_mfma_f32_16x16x32_bf16(a1, bfrag[c][1], acc[c], 0, 0, 0);
        }
        __hip_bfloat16* prow = projr + (size_t)row0 * DIM;
#pragma unroll
        for (int c = 0; c < 4; ++c)
#pragma unroll
            for (int i = 0; i < 4; ++i)
                prow[(q * 4 + i) * DIM + c * 16 + m] = __float2bfloat16(acc[c][i]);
    }
}

// ---------------------------------------------------------------------------
// K3b: per-edge attention logits, 16 edges per wave (2 per 8-lane slot).
// 4 independent 16-B gathers in flight per lane.
// ---------------------------------------------------------------------------
__global__ __launch_bounds__(256) void att_edge_kernel(
        const __hip_bfloat16* __restrict__ proj,
        const float* __restrict__ rel,
        const int* __restrict__ src,
        const int* __restrict__ dst,
        const int* __restrict__ etype,
        const int* __restrict__ row_ptr,
        int* __restrict__ cursor,
        float* __restrict__ att_csr,
        int* __restrict__ src_csr,
        int n_edge) {
    int tid  = blockIdx.x * blockDim.x + threadIdx.x;
    int lane = threadIdx.x & 63;
    int sub  = lane >> 3;
    int q    = lane & 7;
    int e0   = (tid >> 6) * 16 + sub;
    int e1   = e0 + 8;

    bool v0 = e0 < n_edge, v1 = e1 < n_edge;
    int s0 = v0 ? src[e0] : 0, d0 = v0 ? dst[e0] : 0, r0 = v0 ? etype[e0] : 0;
    int s1 = v1 ? src[e1] : 0, d1 = v1 ? dst[e1] : 0, r1 = v1 ? etype[e1] : 0;

    const uint4* pt0 = (const uint4*)(proj + ((size_t)r0 * N_ENT + s0) * DIM + q * 8);
    const uint4* ph0 = (const uint4*)(proj + ((size_t)r0 * N_ENT + d0) * DIM + q * 8);
    const uint4* pt1 = (const uint4*)(proj + ((size_t)r1 * N_ENT + s1) * DIM + q * 8);
    const uint4* ph1 = (const uint4*)(proj + ((size_t)r1 * N_ENT + d1) * DIM + q * 8);
    uint4 ut0 = *pt0, uh0 = *ph0, ut1 = *pt1, uh1 = *ph1;

    const float4* rel0 = (const float4*)(rel + r0 * DIM + q * 8);
    const float4* rel1 = (const float4*)(rel + r1 * DIM + q * 8);
    float4 ra0 = rel0[0], rb0 = rel0[1];
    float4 ra1 = rel1[0], rb1 = rel1[1];

    float tv0[8], hv0[8], tv1[8], hv1[8], rv0[8], rv1[8];
    bf16x8_unpack(ut0, tv0);
    bf16x8_unpack(uh0, hv0);
    bf16x8_unpack(ut1, tv1);
    bf16x8_unpack(uh1, hv1);
    rv0[0]=ra0.x; rv0[1]=ra0.y; rv0[2]=ra0.z; rv0[3]=ra0.w;
    rv0[4]=rb0.x; rv0[5]=rb0.y; rv0[6]=rb0.z; rv0[7]=rb0.w;
    rv1[0]=ra1.x; rv1[1]=ra1.y; rv1[2]=ra1.z; rv1[3]=ra1.w;
    rv1[4]=rb1.x; rv1[5]=rb1.y; rv1[6]=rb1.z; rv1[7]=rb1.w;

    float p0 = 0.f, p1 = 0.f;
#pragma unroll
    for (int j = 0; j < 8; ++j) {
        float x0 = hv0[j] + rv0[j];
        float x1 = hv1[j] + rv1[j];
        float t0 = 1.f - 2.f / (__expf(2.f * x0) + 1.f);
        float t1 = 1.f - 2.f / (__expf(2.f * x1) + 1.f);
        p0 = fmaf(tv0[j], t0, p0);
        p1 = fmaf(tv1[j], t1, p1);
    }
    p0 += __shfl_xor(p0, 1, 64); p1 += __shfl_xor(p1, 1, 64);
    p0 += __shfl_xor(p0, 2, 64); p1 += __shfl_xor(p1, 2, 64);
    p0 += __shfl_xor(p0, 4, 64); p1 += __shfl_xor(p1, 4, 64);

    if (q == 0 && v0) {
        int pos = row_ptr[d0] + atomicAdd(&cursor[d0], 1);
        att_csr[pos] = p0;
        src_csr[pos] = s0;
    }
    if (q == 0 && v1) {
        int pos = row_ptr[d1] + atomicAdd(&cursor[d1], 1);
        att_csr[pos] = p1;
        src_csr[pos] = s1;
    }
}

// ---------------------------------------------------------------------------
// K4: edge softmax per dst node (one wave per node), in-place
// ---------------------------------------------------------------------------
__global__ __launch_bounds__(256) void softmax_kernel(
        const int* __restrict__ row_ptr, float* __restrict__ a_csr, int n_node) {
    int wid  = (blockIdx.x * blockDim.x + threadIdx.x) >> 6;
    int lane = threadIdx.x & 63;
    if (wid >= n_node) return;
    int start = row_ptr[wid], end = row_ptr[wid + 1];

    float m = -INFINITY;
    for (int i = start + lane; i < end; i += 64) m = fmaxf(m, a_csr[i]);
#pragma unroll
    for (int off = 32; off > 0; off >>= 1)
        m = fmaxf(m, __shfl_xor(m, off, 64));

    float ssum = 0.f;
    for (int i = start + lane; i < end; i += 64) {
        float e = expf(a_csr[i] - m);
        a_csr[i] = e;
        ssum += e;
    }
#pragma unroll
    for (int off = 32; off > 0; off >>= 1)
        ssum += __shfl_xor(ssum, off, 64);

    if (end > start) {
        float inv = 1.0f / ssum;
        for (int i = start + lane; i < end; i += 64) a_csr[i] *= inv;
    }
}

// ---------------------------------------------------------------------------
// K5: copy raw ent_embed into out[:, 0:64]
// ---------------------------------------------------------------------------
__global__ __launch_bounds__(256) void copy_ent_kernel(
        const float* __restrict__ ent, float* __restrict__ out, int total) {
    int i = blockIdx.x * blockDim.x + threadIdx.x;
    if (i >= total) return;
    int n = i >> 6, c = i & 63;
    out[(size_t)n * OUT_STRIDE + c] = ent[i];
}

// ---------------------------------------------------------------------------
// K6: bi-interaction layer v3 — high-MLP slot layout.
// LPR lanes per row, 32 B/lane (2 independent uint4 gathers), SLOTS=64/LPR
// edges in flight per wave: D_IN=64 -> LPR=4, 16 edges; D_IN=32 -> LPR=2, 32.
// Lane (q=lane%LPR, sub=lane/LPR) holds dims q*16 + c*8 + j of slot sub.
// ---------------------------------------------------------------------------
template <int D_IN, int D_OUT>
__global__ __launch_bounds__(256) void layer_kernel(
        const ushort* __restrict__ h_bf,      // [N][D_IN] bf16
        const float* __restrict__ W1,
        const float* __restrict__ b1,
        const float* __restrict__ W2,
        const float* __restrict__ b2,
        const int* __restrict__ row_ptr,
        const float* __restrict__ a_csr,
        const int* __restrict__ src_csr,
        ushort* __restrict__ h_out_bf,        // may be null; [N][D_OUT] bf16
        float* __restrict__ out_buf,
        int out_col, int n_node) {
    constexpr int LPR   = D_IN / 16;          // 4 (D_IN=64) or 2 (D_IN=32)
    constexpr int SLOTS = 64 / LPR;           // 16 or 32

    int wid  = (blockIdx.x * blockDim.x + threadIdx.x) >> 6;
    int lane = threadIdx.x & 63;
    if (wid >= n_node) return;
    int q   = lane & (LPR - 1);
    int sub = lane / LPR;

    // own row: dims q*16 + c*8 + j
    const uint4* own = (const uint4*)(h_bf + (size_t)wid * D_IN + q * 16);
    uint4 uo0 = own[0], uo1 = own[1];
    float hv[16];
    bf16x8_unpack(uo0, hv);
    bf16x8_unpack(uo1, hv + 8);

    int start = row_ptr[wid], end = row_ptr[wid + 1];
    float acc[16];
#pragma unroll
    for (int j = 0; j < 16; ++j) acc[j] = 0.f;

    for (int p = start + sub; p < end; p += SLOTS) {
        float av = a_csr[p];
        int   si = src_csr[p];
        const uint4* gp = (const uint4*)(h_bf + (size_t)si * D_IN + q * 16);
        uint4 u0 = gp[0];          // two independent 16-B loads
        uint4 u1 = gp[1];
        float g[16];
        bf16x8_unpack(u0, g);
        bf16x8_unpack(u1, g + 8);
#pragma unroll
        for (int j = 0; j < 16; ++j) acc[j] = fmaf(av, g[j], acc[j]);
    }
    // combine edge slots (xor over lane bits >= log2(LPR))
#pragma unroll
    for (int mask = LPR; mask < 64; mask <<= 1)
#pragma unroll
        for (int j = 0; j < 16; ++j)
            acc[j] += __shfl_xor(acc[j], mask, 64);

    float uu[16], vv[16];
#pragma unroll
    for (int j = 0; j < 16; ++j) {
        uu[j] = hv[j] + acc[j];
        vv[j] = hv[j] * acc[j];
    }

    float o1 = (lane < D_OUT) ? b1[lane] : 0.f;
    float o2 = (lane < D_OUT) ? b2[lane] : 0.f;
#pragma unroll
    for (int k = 0; k < D_IN; ++k) {
        // dim k lives at lane (k>>4), register ((k>>3)&1)*8 + (k&7)
        float uk = __shfl(uu[((k >> 3) & 1) * 8 + (k & 7)], k >> 4, 64);
        float vk = __shfl(vv[((k >> 3) & 1) * 8 + (k & 7)], k >> 4, 64);
        if (lane < D_OUT) {
            o1 = fmaf(uk, W1[k * D_OUT + lane], o1);
            o2 = fmaf(vk, W2[k * D_OUT + lane], o2);
        }
    }
    float r1 = (o1 >= 0.f) ? o1 : 0.01f * o1;
    float r2 = (o2 >= 0.f) ? o2 : 0.01f * o2;
    float res = (lane < D_OUT) ? (r1 + r2) : 0.f;

    float sq = res * res;
#pragma unroll
    for (int off = 32; off > 0; off >>= 1)
        sq += __shfl_xor(sq, off, 64);
    float nrm  = sqrtf(sq);
    float resn = res / fmaxf(nrm, 1e-12f);

    if (lane < D_OUT) {
        if (h_out_bf) {
            __hip_bfloat16 b = __float2bfloat16(res);
            h_out_bf[(size_t)wid * D_OUT + lane] = *(ushort*)&b;
        }
        out_buf[(size_t)wid * OUT_STRIDE + out_col + lane] = resn;
    }
}

// ---------------------------------------------------------------------------
extern "C" void kernel_launch(void* const* d_in, const int* in_sizes, int n_in,
                              void* d_out, int out_size, void* d_ws, size_t ws_size,
                              hipStream_t stream) {
    const float* ent  = (const float*)d_in[0];
    const float* rel  = (const float*)d_in[1];
    const float* W_R  = (const float*)d_in[2];
    const float* W1_0 = (const float*)d_in[3];
    const float* b1_0 = (const float*)d_in[4];
    const float* W2_0 = (const float*)d_in[5];
    const float* b2_0 = (const float*)d_in[6];
    const float* W1_1 = (const float*)d_in[7];
    const float* b1_1 = (const float*)d_in[8];
    const float* W2_1 = (const float*)d_in[9];
    const float* b2_1 = (const float*)d_in[10];
    const float* W1_2 = (const float*)d_in[11];
    const float* b1_2 = (const float*)d_in[12];
    const float* W2_2 = (const float*)d_in[13];
    const float* b2_2 = (const float*)d_in[14];
    const int*   src   = (const int*)d_in[15];
    const int*   dst   = (const int*)d_in[16];
    const int*   etype = (const int*)d_in[17];
    float* out = (float*)d_out;

    // workspace layout
    char* w = (char*)d_ws;
    float*  att_csr = (float*)w;  w += (size_t)N_EDGE * 4;
    int*    src_csr = (int*)w;    w += (size_t)N_EDGE * 4;
    int*    counts  = (int*)w;    w += (size_t)(N_ENT + 64) * 4;
    int*    row_ptr = (int*)w;    w += (size_t)(N_ENT + 64) * 4;
    int*    cursor  = (int*)w;    w += (size_t)(N_ENT + 64) * 4;
    ushort* ent_bf  = (ushort*)w; w += (size_t)N_ENT * 64 * 2;
    ushort* h1_bf   = (ushort*)w; w += (size_t)N_ENT * 64 * 2;
    ushort* h2_bf   = (ushort*)w; w += (size_t)N_ENT * 32 * 2;
    __hip_bfloat16* proj = (__hip_bfloat16*)w;
    size_t need = (size_t)(w - (char*)d_ws) + (size_t)N_RELS * N_ENT * DIM * 2;
    (void)need; (void)ws_size;

    hipMemsetAsync(counts, 0, (size_t)N_ENT * 4, stream);
    hipMemsetAsync(cursor, 0, (size_t)N_ENT * 4, stream);

    hist_kernel<<<(N_EDGE + 255) / 256, 256, 0, stream>>>(dst, counts, N_EDGE);
    scan_kernel<<<1, 1024, 0, stream>>>(counts, row_ptr, N_ENT);
    ent2bf16_kernel<<<(N_ENT * DIM + 255) / 256, 256, 0, stream>>>(
        ent, ent_bf, N_ENT * DIM);

    proj_mfma_kernel<<<dim3(64, N_RELS), 256, 0, stream>>>(ent_bf, W_R, proj);
    att_edge_kernel<<<(N_EDGE + 63) / 64, 256, 0, stream>>>(
        proj, rel, src, dst, etype, row_ptr, cursor, att_csr, src_csr, N_EDGE);

    softmax_kernel<<<(N_ENT + 3) / 4, 256, 0, stream>>>(row_ptr, att_csr, N_ENT);
    copy_ent_kernel<<<(N_ENT * DIM + 255) / 256, 256, 0, stream>>>(ent, out, N_ENT * DIM);

    layer_kernel<64, 64><<<(N_ENT + 3) / 4, 256, 0, stream>>>(
        ent_bf, W1_0, b1_0, W2_0, b2_0, row_ptr, att_csr, src_csr, h1_bf, out, 64, N_ENT);
    layer_kernel<64, 32><<<(N_ENT + 3) / 4, 256, 0, stream>>>(
        h1_bf, W1_1, b1_1, W2_1, b2_1, row_ptr, att_csr, src_csr, h2_bf, out, 128, N_ENT);
    layer_kernel<32, 16><<<(N_ENT + 3) / 4, 256, 0, stream>>>(
        h2_bf, W1_2, b1_2, W2_2, b2_2, row_ptr, att_csr, src_csr, nullptr, out, 160, N_ENT);
}

// Round 7
// 509.799 us; speedup vs baseline: 1.3714x; 1.3714x over previous
//
#include <hip/hip_runtime.h>
#include <hip/hip_bf16.h>
#include <cmath>

#define N_ENT  50000
#define N_RELS 16
#define N_EDGE 1000000
#define DIM    64
#define OUT_STRIDE 176

typedef float f32x4 __attribute__((ext_vector_type(4)));
typedef short s16x8 __attribute__((ext_vector_type(8)));

__device__ inline void bf16x8_unpack(uint4 u, float* f) {
    f[0] = __uint_as_float((u.x & 0xffffu) << 16);
    f[1] = __uint_as_float(u.x & 0xffff0000u);
    f[2] = __uint_as_float((u.y & 0xffffu) << 16);
    f[3] = __uint_as_float(u.y & 0xffff0000u);
    f[4] = __uint_as_float((u.z & 0xffffu) << 16);
    f[5] = __uint_as_float(u.z & 0xffff0000u);
    f[6] = __uint_as_float((u.w & 0xffffu) << 16);
    f[7] = __uint_as_float(u.w & 0xffff0000u);
}

__device__ inline ushort f2bf(float x) {
    __hip_bfloat16 b = __float2bfloat16(x);
    return *(ushort*)&b;
}

// ---------------------------------------------------------------------------
// K0a: convert ent fp32 -> two bf16 planes (dims 0..31 / 32..63)
// ---------------------------------------------------------------------------
__global__ __launch_bounds__(256) void ent2planes_kernel(
        const float* __restrict__ ent,
        ushort* __restrict__ p0, ushort* __restrict__ p1, int total) {
    int i = blockIdx.x * blockDim.x + threadIdx.x;
    if (i >= total) return;
    int n = i >> 6, c = i & 63;
    ushort b = f2bf(ent[i]);
    if (c < 32) p0[n * 32 + c] = b;
    else        p1[n * 32 + (c - 32)] = b;
}

// ---------------------------------------------------------------------------
// K1: histogram of dst -> counts
// ---------------------------------------------------------------------------
__global__ __launch_bounds__(256) void hist_kernel(
        const int* __restrict__ dst, int* __restrict__ counts, int n) {
    int i = blockIdx.x * blockDim.x + threadIdx.x;
    if (i < n) atomicAdd(&counts[dst[i]], 1);
}

// ---------------------------------------------------------------------------
// K2: exclusive scan counts -> row_ptr (single block, 1024 threads)
// ---------------------------------------------------------------------------
__global__ __launch_bounds__(1024) void scan_kernel(
        const int* __restrict__ counts, int* __restrict__ row_ptr, int n) {
    __shared__ int sums[1024];
    int t = threadIdx.x;
    int chunk = (n + 1023) / 1024;
    int start = t * chunk;
    int end = start + chunk; if (end > n) end = n;
    int s = 0;
    for (int i = start; i < end && i >= 0; ++i) s += counts[i];
    sums[t] = s;
    __syncthreads();
    for (int off = 1; off < 1024; off <<= 1) {
        int v = (t >= off) ? sums[t - off] : 0;
        __syncthreads();
        sums[t] += v;
        __syncthreads();
    }
    int prefix = (t == 0) ? 0 : sums[t - 1];
    for (int i = start; i < end; ++i) {
        row_ptr[i] = prefix;
        prefix += counts[i];
    }
    if (end == n) row_ptr[n] = prefix;
}

// ---------------------------------------------------------------------------
// K3a: proj[r] = ent @ W_R[r] via bf16 MFMA; A-rows from the two ent planes.
// ---------------------------------------------------------------------------
__global__ __launch_bounds__(256) void proj_mfma_kernel(
        const ushort* __restrict__ ent_p0,
        const ushort* __restrict__ ent_p1,
        const float*  __restrict__ W_R,
        __hip_bfloat16* __restrict__ proj) {
    int lane = threadIdx.x & 63;
    int m    = lane & 15;
    int q    = lane >> 4;
    int r    = blockIdx.y;
    int wid  = blockIdx.x * (blockDim.x >> 6) + (threadIdx.x >> 6);
    int nw   = gridDim.x * (blockDim.x >> 6);

    const float* Wr = W_R + (size_t)r * DIM * DIM;
    s16x8 bfrag[4][2];
#pragma unroll
    for (int c = 0; c < 4; ++c)
#pragma unroll
        for (int ch = 0; ch < 2; ++ch)
#pragma unroll
            for (int j = 0; j < 8; ++j)
                bfrag[c][ch][j] = (short)f2bf(Wr[(ch * 32 + q * 8 + j) * DIM + c * 16 + m]);

    __hip_bfloat16* projr = proj + (size_t)r * N_ENT * DIM;
    const int ntiles = N_ENT / 16;

    for (int t = wid; t < ntiles; t += nw) {
        int row0 = t * 16;
        s16x8 a0 = *(const s16x8*)(ent_p0 + (size_t)(row0 + m) * 32 + q * 8);
        s16x8 a1 = *(const s16x8*)(ent_p1 + (size_t)(row0 + m) * 32 + q * 8);
        f32x4 acc[4];
#pragma unroll
        for (int c = 0; c < 4; ++c) acc[c] = (f32x4){0.f, 0.f, 0.f, 0.f};
#pragma unroll
        for (int c = 0; c < 4; ++c) {
            acc[c] = __builtin_amdgcn_mfma_f32_16x16x32_bf16(a0, bfrag[c][0], acc[c], 0, 0, 0);
            acc[c] = __builtin_amdgcn_mfma_f32_16x16x32_bf16(a1, bfrag[c][1], acc[c], 0, 0, 0);
        }
        __hip_bfloat16* prow = projr + (size_t)row0 * DIM;
#pragma unroll
        for (int c = 0; c < 4; ++c)
#pragma unroll
            for (int i = 0; i < 4; ++i)
                prow[(q * 4 + i) * DIM + c * 16 + m] = __float2bfloat16(acc[c][i]);
    }
}

// ---------------------------------------------------------------------------
// K3b: per-edge attention logits, 8 edges per wave (round-5 shape).
// ---------------------------------------------------------------------------
__global__ __launch_bounds__(256) void att_edge_kernel(
        const __hip_bfloat16* __restrict__ proj,
        const float* __restrict__ rel,
        const int* __restrict__ src,
        const int* __restrict__ dst,
        const int* __restrict__ etype,
        const int* __restrict__ row_ptr,
        int* __restrict__ cursor,
        float* __restrict__ att_csr,
        int* __restrict__ src_csr,
        int n_edge) {
    int tid  = blockIdx.x * blockDim.x + threadIdx.x;
    int lane = threadIdx.x & 63;
    int sub  = lane >> 3;
    int q    = lane & 7;
    int e    = (tid >> 6) * 8 + sub;
    if (e >= n_edge) return;

    int s = src[e];
    int d = dst[e];
    int r = etype[e];

    uint4 ut = *(const uint4*)(proj + ((size_t)r * N_ENT + s) * DIM + q * 8);
    uint4 uh = *(const uint4*)(proj + ((size_t)r * N_ENT + d) * DIM + q * 8);
    const float4* relv = (const float4*)(rel + r * DIM + q * 8);
    float4 ra = relv[0], rb = relv[1];

    float tv[8], hv[8], rv[8];
    bf16x8_unpack(ut, tv);
    bf16x8_unpack(uh, hv);
    rv[0] = ra.x; rv[1] = ra.y; rv[2] = ra.z; rv[3] = ra.w;
    rv[4] = rb.x; rv[5] = rb.y; rv[6] = rb.z; rv[7] = rb.w;

    float prod = 0.f;
#pragma unroll
    for (int j = 0; j < 8; ++j) {
        float x   = hv[j] + rv[j];
        float e2x = __expf(2.f * x);
        float th  = 1.f - 2.f / (e2x + 1.f);
        prod = fmaf(tv[j], th, prod);
    }
    prod += __shfl_xor(prod, 1, 64);
    prod += __shfl_xor(prod, 2, 64);
    prod += __shfl_xor(prod, 4, 64);

    if (q == 0) {
        int pos = row_ptr[d] + atomicAdd(&cursor[d], 1);
        att_csr[pos] = prod;
        src_csr[pos] = s;
    }
}

// ---------------------------------------------------------------------------
// K4: edge softmax per dst node (one wave per node), in-place
// ---------------------------------------------------------------------------
__global__ __launch_bounds__(256) void softmax_kernel(
        const int* __restrict__ row_ptr, float* __restrict__ a_csr, int n_node) {
    int wid  = (blockIdx.x * blockDim.x + threadIdx.x) >> 6;
    int lane = threadIdx.x & 63;
    if (wid >= n_node) return;
    int start = row_ptr[wid], end = row_ptr[wid + 1];

    float m = -INFINITY;
    for (int i = start + lane; i < end; i += 64) m = fmaxf(m, a_csr[i]);
#pragma unroll
    for (int off = 32; off > 0; off >>= 1)
        m = fmaxf(m, __shfl_xor(m, off, 64));

    float ssum = 0.f;
    for (int i = start + lane; i < end; i += 64) {
        float e = expf(a_csr[i] - m);
        a_csr[i] = e;
        ssum += e;
    }
#pragma unroll
    for (int off = 32; off > 0; off >>= 1)
        ssum += __shfl_xor(ssum, off, 64);

    if (end > start) {
        float inv = 1.0f / ssum;
        for (int i = start + lane; i < end; i += 64) a_csr[i] *= inv;
    }
}

// ---------------------------------------------------------------------------
// K5: copy raw ent_embed into out[:, 0:64]
// ---------------------------------------------------------------------------
__global__ __launch_bounds__(256) void copy_ent_kernel(
        const float* __restrict__ ent, float* __restrict__ out, int total) {
    int i = blockIdx.x * blockDim.x + threadIdx.x;
    if (i >= total) return;
    int n = i >> 6, c = i & 63;
    out[(size_t)n * OUT_STRIDE + c] = ent[i];
}

// ---------------------------------------------------------------------------
// K6a: aggregation over one 32-dim plane (L2-resident 3.2 MB table).
// One wave per node; 16 edge slots (4 lanes x 16 B per row-slice).
// N_h[wid*stride + off + 0..31] = sum_edges a * plane[src].
// ---------------------------------------------------------------------------
__global__ __launch_bounds__(256) void agg_kernel(
        const ushort* __restrict__ plane,    // [N][32] bf16
        const float* __restrict__ a_csr,
        const int* __restrict__ src_csr,
        const int* __restrict__ row_ptr,
        float* __restrict__ N_h, int stride, int off, int n_node) {
    int wid  = (blockIdx.x * blockDim.x + threadIdx.x) >> 6;
    int lane = threadIdx.x & 63;
    if (wid >= n_node) return;
    int q   = lane & 3;       // 8-dim slice within the 32-dim row
    int sub = lane >> 2;      // edge slot 0..15

    int start = row_ptr[wid], end = row_ptr[wid + 1];
    float acc[8];
#pragma unroll
    for (int j = 0; j < 8; ++j) acc[j] = 0.f;

    for (int p = start + sub; p < end; p += 16) {
        float av = a_csr[p];
        int   si = src_csr[p];
        uint4 u  = *(const uint4*)(plane + (size_t)si * 32 + q * 8);
        float g[8];
        bf16x8_unpack(u, g);
#pragma unroll
        for (int j = 0; j < 8; ++j) acc[j] = fmaf(av, g[j], acc[j]);
    }
#pragma unroll
    for (int mask = 4; mask < 64; mask <<= 1)
#pragma unroll
        for (int j = 0; j < 8; ++j)
            acc[j] += __shfl_xor(acc[j], mask, 64);

    if (sub == 0) {
        float* dstp = N_h + (size_t)wid * stride + off + q * 8;
        *(float4*)(dstp)     = (float4){acc[0], acc[1], acc[2], acc[3]};
        *(float4*)(dstp + 4) = (float4){acc[4], acc[5], acc[6], acc[7]};
    }
}

// ---------------------------------------------------------------------------
// K6b: dense bi-interaction MLP via MFMA, fused bias/leaky/l2-norm epilogue.
//   res = leaky((h+N_h)@W1+b1) + leaky((h*N_h)@W2+b2)
//   out[:, out_col..] = l2norm(res); next-h planes (bf16, unnormalized).
// One wave per 16-row tile (grid-stride). CH = D_IN/32 k-chunks, CT = D_OUT/16.
// ---------------------------------------------------------------------------
template <int D_IN, int D_OUT>
__global__ __launch_bounds__(256) void mlp_mfma_kernel(
        const ushort* __restrict__ h_p0,    // [N][32] dims 0..31 (or flat D_IN=32)
        const ushort* __restrict__ h_p1,    // [N][32] dims 32..63 (null if D_IN=32)
        const float* __restrict__ N_h,      // [N][D_IN] fp32
        const float* __restrict__ W1, const float* __restrict__ b1,
        const float* __restrict__ W2, const float* __restrict__ b2,
        ushort* __restrict__ ho_p0,         // next-h plane0 / flat (or null)
        ushort* __restrict__ ho_p1,         // next-h plane1 (or null)
        float* __restrict__ out_buf, int out_col) {
    constexpr int CH = D_IN / 32;
    constexpr int CT = D_OUT / 16;

    int lane = threadIdx.x & 63;
    int m    = lane & 15;
    int q    = lane >> 4;
    int wid  = blockIdx.x * (blockDim.x >> 6) + (threadIdx.x >> 6);
    int nw   = gridDim.x * (blockDim.x >> 6);

    // B fragments for both GEMMs (bf16-converted once)
    s16x8 bu[CT][CH], bv[CT][CH];
#pragma unroll
    for (int c = 0; c < CT; ++c)
#pragma unroll
        for (int ch = 0; ch < CH; ++ch)
#pragma unroll
            for (int j = 0; j < 8; ++j) {
                int k = ch * 32 + q * 8 + j;
                bu[c][ch][j] = (short)f2bf(W1[k * D_OUT + c * 16 + m]);
                bv[c][ch][j] = (short)f2bf(W2[k * D_OUT + c * 16 + m]);
            }
    float bias1 = 0.f, bias2 = 0.f;
    {
        // per-lane biases for each col tile handled in epilogue loop below
    }

    const int ntiles = N_ENT / 16;
    for (int t = wid; t < ntiles; t += nw) {
        int row0 = t * 16;
        // A fragments: u = h + N_h, v = h * N_h (per k-chunk)
        s16x8 au[CH], av[CH];
#pragma unroll
        for (int ch = 0; ch < CH; ++ch) {
            const ushort* hp = (ch == 0) ? h_p0 : h_p1;
            uint4 hu = *(const uint4*)(hp + (size_t)(row0 + m) * 32 + q * 8);
            float hv8[8];
            bf16x8_unpack(hu, hv8);
            const float4* np = (const float4*)(N_h + (size_t)(row0 + m) * D_IN + ch * 32 + q * 8);
            float4 na = np[0], nb = np[1];
            float nv[8] = {na.x, na.y, na.z, na.w, nb.x, nb.y, nb.z, nb.w};
#pragma unroll
            for (int j = 0; j < 8; ++j) {
                au[ch][j] = (short)f2bf(hv8[j] + nv[j]);
                av[ch][j] = (short)f2bf(hv8[j] * nv[j]);
            }
        }

        f32x4 accu[CT], accv[CT];
#pragma unroll
        for (int c = 0; c < CT; ++c) {
            accu[c] = (f32x4){0.f, 0.f, 0.f, 0.f};
            accv[c] = (f32x4){0.f, 0.f, 0.f, 0.f};
        }
#pragma unroll
        for (int c = 0; c < CT; ++c)
#pragma unroll
            for (int ch = 0; ch < CH; ++ch) {
                accu[c] = __builtin_amdgcn_mfma_f32_16x16x32_bf16(au[ch], bu[c][ch], accu[c], 0, 0, 0);
                accv[c] = __builtin_amdgcn_mfma_f32_16x16x32_bf16(av[ch], bv[c][ch], accv[c], 0, 0, 0);
            }

        // epilogue: bias + leaky + sum, then per-row l2 norm
        float res[CT][4];
        float sq[4] = {0.f, 0.f, 0.f, 0.f};
#pragma unroll
        for (int c = 0; c < CT; ++c) {
            float bb1 = b1[c * 16 + m];
            float bb2 = b2[c * 16 + m];
#pragma unroll
            for (int i = 0; i < 4; ++i) {
                float o1 = accu[c][i] + bb1;
                float o2 = accv[c][i] + bb2;
                float r1 = (o1 >= 0.f) ? o1 : 0.01f * o1;
                float r2 = (o2 >= 0.f) ? o2 : 0.01f * o2;
                float rr = r1 + r2;
                res[c][i] = rr;
                sq[i] = fmaf(rr, rr, sq[i]);
            }
        }
        // reduce sq across the 16 lanes of this row-group (xor bits 0..3)
#pragma unroll
        for (int mask = 1; mask < 16; mask <<= 1)
#pragma unroll
            for (int i = 0; i < 4; ++i)
                sq[i] += __shfl_xor(sq[i], mask, 64);

#pragma unroll
        for (int i = 0; i < 4; ++i) {
            int row = row0 + q * 4 + i;
            float inv = 1.f / fmaxf(sqrtf(sq[i]), 1e-12f);
#pragma unroll
            for (int c = 0; c < CT; ++c) {
                int col = c * 16 + m;
                out_buf[(size_t)row * OUT_STRIDE + out_col + col] = res[c][i] * inv;
                if (ho_p0) {
                    ushort hb = f2bf(res[c][i]);
                    if (col < 32) ho_p0[(size_t)row * 32 + col] = hb;
                    else          ho_p1[(size_t)row * 32 + (col - 32)] = hb;
                }
            }
        }
    }
}

// ---------------------------------------------------------------------------
extern "C" void kernel_launch(void* const* d_in, const int* in_sizes, int n_in,
                              void* d_out, int out_size, void* d_ws, size_t ws_size,
                              hipStream_t stream) {
    const float* ent  = (const float*)d_in[0];
    const float* rel  = (const float*)d_in[1];
    const float* W_R  = (const float*)d_in[2];
    const float* W1_0 = (const float*)d_in[3];
    const float* b1_0 = (const float*)d_in[4];
    const float* W2_0 = (const float*)d_in[5];
    const float* b2_0 = (const float*)d_in[6];
    const float* W1_1 = (const float*)d_in[7];
    const float* b1_1 = (const float*)d_in[8];
    const float* W2_1 = (const float*)d_in[9];
    const float* b2_1 = (const float*)d_in[10];
    const float* W1_2 = (const float*)d_in[11];
    const float* b1_2 = (const float*)d_in[12];
    const float* W2_2 = (const float*)d_in[13];
    const float* b2_2 = (const float*)d_in[14];
    const int*   src   = (const int*)d_in[15];
    const int*   dst   = (const int*)d_in[16];
    const int*   etype = (const int*)d_in[17];
    float* out = (float*)d_out;

    // workspace layout
    char* w = (char*)d_ws;
    float*  att_csr = (float*)w;  w += (size_t)N_EDGE * 4;              // 4 MB
    int*    src_csr = (int*)w;    w += (size_t)N_EDGE * 4;              // 4 MB
    int*    counts  = (int*)w;    w += (size_t)(N_ENT + 64) * 4;
    int*    row_ptr = (int*)w;    w += (size_t)(N_ENT + 64) * 4;
    int*    cursor  = (int*)w;    w += (size_t)(N_ENT + 64) * 4;
    ushort* ent_p0  = (ushort*)w; w += (size_t)N_ENT * 32 * 2;          // 3.2 MB
    ushort* ent_p1  = (ushort*)w; w += (size_t)N_ENT * 32 * 2;          // 3.2 MB
    ushort* h1_p0   = (ushort*)w; w += (size_t)N_ENT * 32 * 2;          // 3.2 MB
    ushort* h1_p1   = (ushort*)w; w += (size_t)N_ENT * 32 * 2;          // 3.2 MB
    ushort* h2      = (ushort*)w; w += (size_t)N_ENT * 32 * 2;          // 3.2 MB
    float*  N_h     = (float*)w;  w += (size_t)N_ENT * 64 * 4;          // 12.8 MB
    __hip_bfloat16* proj = (__hip_bfloat16*)w;                          // 102 MB
    (void)ws_size;

    hipMemsetAsync(counts, 0, (size_t)N_ENT * 4, stream);
    hipMemsetAsync(cursor, 0, (size_t)N_ENT * 4, stream);

    hist_kernel<<<(N_EDGE + 255) / 256, 256, 0, stream>>>(dst, counts, N_EDGE);
    scan_kernel<<<1, 1024, 0, stream>>>(counts, row_ptr, N_ENT);
    ent2planes_kernel<<<(N_ENT * DIM + 255) / 256, 256, 0, stream>>>(
        ent, ent_p0, ent_p1, N_ENT * DIM);

    proj_mfma_kernel<<<dim3(64, N_RELS), 256, 0, stream>>>(ent_p0, ent_p1, W_R, proj);
    att_edge_kernel<<<((N_EDGE + 7) / 8 * 64 + 255) / 256, 256, 0, stream>>>(
        proj, rel, src, dst, etype, row_ptr, cursor, att_csr, src_csr, N_EDGE);

    softmax_kernel<<<(N_ENT + 3) / 4, 256, 0, stream>>>(row_ptr, att_csr, N_ENT);
    copy_ent_kernel<<<(N_ENT * DIM + 255) / 256, 256, 0, stream>>>(ent, out, N_ENT * DIM);

    const int aggGrid = (N_ENT + 3) / 4;
    const int mlpGrid = 782;   // 782*4 waves ~= 3128 >= 3125 tiles

    // ---- layer 0: D_IN=64 (ent planes) -> D_OUT=64 (h1 planes) ----
    agg_kernel<<<aggGrid, 256, 0, stream>>>(ent_p0, att_csr, src_csr, row_ptr, N_h, 64, 0,  N_ENT);
    agg_kernel<<<aggGrid, 256, 0, stream>>>(ent_p1, att_csr, src_csr, row_ptr, N_h, 64, 32, N_ENT);
    mlp_mfma_kernel<64, 64><<<mlpGrid, 256, 0, stream>>>(
        ent_p0, ent_p1, N_h, W1_0, b1_0, W2_0, b2_0, h1_p0, h1_p1, out, 64);

    // ---- layer 1: D_IN=64 (h1 planes) -> D_OUT=32 (h2 flat) ----
    agg_kernel<<<aggGrid, 256, 0, stream>>>(h1_p0, att_csr, src_csr, row_ptr, N_h, 64, 0,  N_ENT);
    agg_kernel<<<aggGrid, 256, 0, stream>>>(h1_p1, att_csr, src_csr, row_ptr, N_h, 64, 32, N_ENT);
    mlp_mfma_kernel<64, 32><<<mlpGrid, 256, 0, stream>>>(
        h1_p0, h1_p1, N_h, W1_1, b1_1, W2_1, b2_1, h2, nullptr, out, 128);

    // ---- layer 2: D_IN=32 (h2 flat, fully L2-resident) -> D_OUT=16 ----
    agg_kernel<<<aggGrid, 256, 0, stream>>>(h2, att_csr, src_csr, row_ptr, N_h, 32, 0, N_ENT);
    mlp_mfma_kernel<32, 16><<<mlpGrid, 256, 0, stream>>>(
        h2, nullptr, N_h, W1_2, b1_2, W2_2, b2_2, nullptr, nullptr, out, 160);
}

// Round 8
// 454.861 us; speedup vs baseline: 1.5370x; 1.1208x over previous
//
#include <hip/hip_runtime.h>
#include <hip/hip_bf16.h>
#include <cmath>

#define N_ENT  50000
#define N_RELS 16
#define N_EDGE 1000000
#define DIM    64
#define OUT_STRIDE 176

typedef float f32x4 __attribute__((ext_vector_type(4)));
typedef short s16x8 __attribute__((ext_vector_type(8)));

__device__ inline void bf16x8_unpack(uint4 u, float* f) {
    f[0] = __uint_as_float((u.x & 0xffffu) << 16);
    f[1] = __uint_as_float(u.x & 0xffff0000u);
    f[2] = __uint_as_float((u.y & 0xffffu) << 16);
    f[3] = __uint_as_float(u.y & 0xffff0000u);
    f[4] = __uint_as_float((u.z & 0xffffu) << 16);
    f[5] = __uint_as_float(u.z & 0xffff0000u);
    f[6] = __uint_as_float((u.w & 0xffffu) << 16);
    f[7] = __uint_as_float(u.w & 0xffff0000u);
}

__device__ inline ushort f2bf(float x) {
    __hip_bfloat16 b = __float2bfloat16(x);
    return *(ushort*)&b;
}

// ---------------------------------------------------------------------------
// K0: ent fp32 -> bf16 flat + two 32-dim planes + out[:,0:64] copy (fused)
// ---------------------------------------------------------------------------
__global__ __launch_bounds__(256) void ent_prep_kernel(
        const float* __restrict__ ent,
        ushort* __restrict__ ent_bf,
        ushort* __restrict__ p0, ushort* __restrict__ p1,
        float* __restrict__ out, int total) {
    int i = blockIdx.x * blockDim.x + threadIdx.x;
    if (i >= total) return;
    float v = ent[i];
    ushort b = f2bf(v);
    int n = i >> 6, c = i & 63;
    ent_bf[i] = b;
    if (c < 32) p0[n * 32 + c] = b;
    else        p1[n * 32 + (c - 32)] = b;
    out[(size_t)n * OUT_STRIDE + c] = v;
}

// ---------------------------------------------------------------------------
// K1: histogram of dst -> counts
// ---------------------------------------------------------------------------
__global__ __launch_bounds__(256) void hist_kernel(
        const int* __restrict__ dst, int* __restrict__ counts, int n) {
    int i = blockIdx.x * blockDim.x + threadIdx.x;
    if (i < n) atomicAdd(&counts[dst[i]], 1);
}

// ---------------------------------------------------------------------------
// K2: 3-phase multi-block exclusive scan counts -> row_ptr
// ---------------------------------------------------------------------------
__global__ __launch_bounds__(256) void scan1_kernel(
        const int* __restrict__ counts, int* __restrict__ excl,
        int* __restrict__ bsum, int n) {
    __shared__ int sh[256];
    int t = threadIdx.x;
    int i = blockIdx.x * 256 + t;
    int c = (i < n) ? counts[i] : 0;
    sh[t] = c;
    __syncthreads();
    for (int off = 1; off < 256; off <<= 1) {
        int v = (t >= off) ? sh[t - off] : 0;
        __syncthreads();
        sh[t] += v;
        __syncthreads();
    }
    if (i < n) excl[i] = sh[t] - c;
    if (t == 255) bsum[blockIdx.x] = sh[255];
}

__global__ __launch_bounds__(256) void scan2_kernel(
        const int* __restrict__ bsum, int* __restrict__ boff,
        int* __restrict__ row_ptr, int nb, int n) {
    __shared__ int sh[256];
    int t = threadIdx.x;
    int v = (t < nb) ? bsum[t] : 0;
    sh[t] = v;
    __syncthreads();
    for (int off = 1; off < 256; off <<= 1) {
        int x = (t >= off) ? sh[t - off] : 0;
        __syncthreads();
        sh[t] += x;
        __syncthreads();
    }
    if (t < nb) boff[t] = sh[t] - v;
    if (t == nb - 1) row_ptr[n] = sh[t];
}

__global__ __launch_bounds__(256) void scan3_kernel(
        const int* __restrict__ excl, const int* __restrict__ boff,
        int* __restrict__ row_ptr, int n) {
    int i = blockIdx.x * blockDim.x + threadIdx.x;
    if (i < n) row_ptr[i] = excl[i] + boff[i >> 8];
}

// ---------------------------------------------------------------------------
// K3a: fused G->Z kernel.
//   G_r = tanh(ent @ W_r + rel_r)          (registers, per 16-row tile)
//   Z_r = G_r @ W_r^T                      (via LDS transpose, bf16 out)
// att logit then = ent_s . Z[r][d]  (exact algebraic refactor).
// Per-wave LDS f32 tile, row stride 68 (2-way bank alias only).
// ---------------------------------------------------------------------------
__global__ __launch_bounds__(256) void gz_mfma_kernel(
        const ushort* __restrict__ ent_bf,   // [N][64] bf16
        const float*  __restrict__ W_R,      // [16][64][64] fp32
        const float*  __restrict__ rel,      // [16][64] fp32
        __hip_bfloat16* __restrict__ Z) {    // [16][N][64] bf16
    __shared__ float lds[4][16 * 68 + 16];
    int lane = threadIdx.x & 63;
    int wv   = threadIdx.x >> 6;
    int m    = lane & 15;
    int q    = lane >> 4;
    int r    = blockIdx.y;
    int wid  = blockIdx.x * 4 + wv;
    int nw   = gridDim.x * 4;

    const float* Wr = W_R + (size_t)r * DIM * DIM;
    s16x8 b1[4][2], b2[4][2];
#pragma unroll
    for (int c = 0; c < 4; ++c)
#pragma unroll
        for (int ch = 0; ch < 2; ++ch)
#pragma unroll
            for (int j = 0; j < 8; ++j) {
                // B1[k][n] = W_r[k][n],  k = ch*32+q*8+j, n = c*16+m
                b1[c][ch][j] = (short)f2bf(Wr[(ch * 32 + q * 8 + j) * DIM + c * 16 + m]);
                // B2[j'][n] = W_r^T[j'][n] = W_r[n][j'], j' = ch*32+q*8+j, n = c*16+m
                b2[c][ch][j] = (short)f2bf(Wr[(c * 16 + m) * DIM + ch * 32 + q * 8 + j]);
            }
    float relv[4];
#pragma unroll
    for (int c = 0; c < 4; ++c) relv[c] = rel[r * DIM + c * 16 + m];

    float* myLds = lds[wv];
    const int ntiles = N_ENT / 16;

    for (int t = wid; t < ntiles; t += nw) {
        int row0 = t * 16;
        const s16x8* arow = (const s16x8*)(ent_bf + (size_t)(row0 + m) * DIM);
        s16x8 a0 = arow[q];
        s16x8 a1 = arow[4 + q];
        f32x4 acc[4];
#pragma unroll
        for (int c = 0; c < 4; ++c) acc[c] = (f32x4){0.f, 0.f, 0.f, 0.f};
#pragma unroll
        for (int c = 0; c < 4; ++c) {
            acc[c] = __builtin_amdgcn_mfma_f32_16x16x32_bf16(a0, b1[c][0], acc[c], 0, 0, 0);
            acc[c] = __builtin_amdgcn_mfma_f32_16x16x32_bf16(a1, b1[c][1], acc[c], 0, 0, 0);
        }
        // epilogue: G = tanh(acc + rel), write to LDS in [row][col] form
        // C-layout: row = q*4+i, col = c*16+m
#pragma unroll
        for (int c = 0; c < 4; ++c)
#pragma unroll
            for (int i = 0; i < 4; ++i) {
                float x = acc[c][i] + relv[c];
                float g = 1.f - 2.f / (__expf(2.f * x) + 1.f);
                myLds[(q * 4 + i) * 68 + c * 16 + m] = g;
            }
        // A2 fragments: A2[m][j'] = G[m][j'], j' = ch*32 + q*8 + j
        s16x8 a2[2];
#pragma unroll
        for (int ch = 0; ch < 2; ++ch)
#pragma unroll
            for (int j = 0; j < 8; ++j)
                a2[ch][j] = (short)f2bf(myLds[m * 68 + ch * 32 + q * 8 + j]);

        f32x4 zacc[4];
#pragma unroll
        for (int c = 0; c < 4; ++c) zacc[c] = (f32x4){0.f, 0.f, 0.f, 0.f};
#pragma unroll
        for (int c = 0; c < 4; ++c) {
            zacc[c] = __builtin_amdgcn_mfma_f32_16x16x32_bf16(a2[0], b2[c][0], zacc[c], 0, 0, 0);
            zacc[c] = __builtin_amdgcn_mfma_f32_16x16x32_bf16(a2[1], b2[c][1], zacc[c], 0, 0, 0);
        }
        __hip_bfloat16* zrow = Z + ((size_t)r * N_ENT + row0) * DIM;
#pragma unroll
        for (int c = 0; c < 4; ++c)
#pragma unroll
            for (int i = 0; i < 4; ++i)
                zrow[(q * 4 + i) * DIM + c * 16 + m] = __float2bfloat16(zacc[c][i]);
    }
}

// ---------------------------------------------------------------------------
// K3b: per-edge logit = dot(ent_bf[s], Z[r][d]). 8 edges/wave, CSR fill.
// ---------------------------------------------------------------------------
__global__ __launch_bounds__(256) void att_dot_kernel(
        const ushort* __restrict__ ent_bf,
        const __hip_bfloat16* __restrict__ Z,
        const int* __restrict__ src,
        const int* __restrict__ dst,
        const int* __restrict__ etype,
        const int* __restrict__ row_ptr,
        int* __restrict__ cursor,
        float* __restrict__ att_csr,
        int* __restrict__ src_csr,
        int n_edge) {
    int tid  = blockIdx.x * blockDim.x + threadIdx.x;
    int lane = threadIdx.x & 63;
    int sub  = lane >> 3;
    int q    = lane & 7;
    int e    = (tid >> 6) * 8 + sub;
    if (e >= n_edge) return;

    int s = src[e];
    int d = dst[e];
    int r = etype[e];

    uint4 uz = *(const uint4*)(Z + ((size_t)r * N_ENT + d) * DIM + q * 8);
    uint4 ue = *(const uint4*)(ent_bf + (size_t)s * DIM + q * 8);

    float zv[8], ev[8];
    bf16x8_unpack(uz, zv);
    bf16x8_unpack(ue, ev);

    float prod = 0.f;
#pragma unroll
    for (int j = 0; j < 8; ++j) prod = fmaf(ev[j], zv[j], prod);
    prod += __shfl_xor(prod, 1, 64);
    prod += __shfl_xor(prod, 2, 64);
    prod += __shfl_xor(prod, 4, 64);

    if (q == 0) {
        int pos = row_ptr[d] + atomicAdd(&cursor[d], 1);
        att_csr[pos] = prod;
        src_csr[pos] = s;
    }
}

// ---------------------------------------------------------------------------
// K4: edge softmax per dst node (one wave per node), in-place
// ---------------------------------------------------------------------------
__global__ __launch_bounds__(256) void softmax_kernel(
        const int* __restrict__ row_ptr, float* __restrict__ a_csr, int n_node) {
    int wid  = (blockIdx.x * blockDim.x + threadIdx.x) >> 6;
    int lane = threadIdx.x & 63;
    if (wid >= n_node) return;
    int start = row_ptr[wid], end = row_ptr[wid + 1];

    float m = -INFINITY;
    for (int i = start + lane; i < end; i += 64) m = fmaxf(m, a_csr[i]);
#pragma unroll
    for (int off = 32; off > 0; off >>= 1)
        m = fmaxf(m, __shfl_xor(m, off, 64));

    float ssum = 0.f;
    for (int i = start + lane; i < end; i += 64) {
        float e = expf(a_csr[i] - m);
        a_csr[i] = e;
        ssum += e;
    }
#pragma unroll
    for (int off = 32; off > 0; off >>= 1)
        ssum += __shfl_xor(ssum, off, 64);

    if (end > start) {
        float inv = 1.0f / ssum;
        for (int i = start + lane; i < end; i += 64) a_csr[i] *= inv;
    }
}

// ---------------------------------------------------------------------------
// K6a: aggregation over one 32-dim plane (L2-resident 3.2 MB table).
// ---------------------------------------------------------------------------
__global__ __launch_bounds__(256) void agg_kernel(
        const ushort* __restrict__ plane,    // [N][32] bf16
        const float* __restrict__ a_csr,
        const int* __restrict__ src_csr,
        const int* __restrict__ row_ptr,
        float* __restrict__ N_h, int stride, int off, int n_node) {
    int wid  = (blockIdx.x * blockDim.x + threadIdx.x) >> 6;
    int lane = threadIdx.x & 63;
    if (wid >= n_node) return;
    int q   = lane & 3;
    int sub = lane >> 2;

    int start = row_ptr[wid], end = row_ptr[wid + 1];
    float acc[8];
#pragma unroll
    for (int j = 0; j < 8; ++j) acc[j] = 0.f;

    for (int p = start + sub; p < end; p += 16) {
        float av = a_csr[p];
        int   si = src_csr[p];
        uint4 u  = *(const uint4*)(plane + (size_t)si * 32 + q * 8);
        float g[8];
        bf16x8_unpack(u, g);
#pragma unroll
        for (int j = 0; j < 8; ++j) acc[j] = fmaf(av, g[j], acc[j]);
    }
#pragma unroll
    for (int mask = 4; mask < 64; mask <<= 1)
#pragma unroll
        for (int j = 0; j < 8; ++j)
            acc[j] += __shfl_xor(acc[j], mask, 64);

    if (sub == 0) {
        float* dstp = N_h + (size_t)wid * stride + off + q * 8;
        *(float4*)(dstp)     = (float4){acc[0], acc[1], acc[2], acc[3]};
        *(float4*)(dstp + 4) = (float4){acc[4], acc[5], acc[6], acc[7]};
    }
}

// ---------------------------------------------------------------------------
// K6b: dense bi-interaction MLP via MFMA, fused bias/leaky/l2-norm epilogue.
// ---------------------------------------------------------------------------
template <int D_IN, int D_OUT>
__global__ __launch_bounds__(256) void mlp_mfma_kernel(
        const ushort* __restrict__ h_p0,
        const ushort* __restrict__ h_p1,
        const float* __restrict__ N_h,
        const float* __restrict__ W1, const float* __restrict__ b1,
        const float* __restrict__ W2, const float* __restrict__ b2,
        ushort* __restrict__ ho_p0,
        ushort* __restrict__ ho_p1,
        float* __restrict__ out_buf, int out_col) {
    constexpr int CH = D_IN / 32;
    constexpr int CT = D_OUT / 16;

    int lane = threadIdx.x & 63;
    int m    = lane & 15;
    int q    = lane >> 4;
    int wid  = blockIdx.x * (blockDim.x >> 6) + (threadIdx.x >> 6);
    int nw   = gridDim.x * (blockDim.x >> 6);

    s16x8 bu[CT][CH], bv[CT][CH];
#pragma unroll
    for (int c = 0; c < CT; ++c)
#pragma unroll
        for (int ch = 0; ch < CH; ++ch)
#pragma unroll
            for (int j = 0; j < 8; ++j) {
                int k = ch * 32 + q * 8 + j;
                bu[c][ch][j] = (short)f2bf(W1[k * D_OUT + c * 16 + m]);
                bv[c][ch][j] = (short)f2bf(W2[k * D_OUT + c * 16 + m]);
            }

    const int ntiles = N_ENT / 16;
    for (int t = wid; t < ntiles; t += nw) {
        int row0 = t * 16;
        s16x8 au[CH], av[CH];
#pragma unroll
        for (int ch = 0; ch < CH; ++ch) {
            const ushort* hp = (ch == 0) ? h_p0 : h_p1;
            uint4 hu = *(const uint4*)(hp + (size_t)(row0 + m) * 32 + q * 8);
            float hv8[8];
            bf16x8_unpack(hu, hv8);
            const float4* np = (const float4*)(N_h + (size_t)(row0 + m) * D_IN + ch * 32 + q * 8);
            float4 na = np[0], nb = np[1];
            float nv[8] = {na.x, na.y, na.z, na.w, nb.x, nb.y, nb.z, nb.w};
#pragma unroll
            for (int j = 0; j < 8; ++j) {
                au[ch][j] = (short)f2bf(hv8[j] + nv[j]);
                av[ch][j] = (short)f2bf(hv8[j] * nv[j]);
            }
        }

        f32x4 accu[CT], accv[CT];
#pragma unroll
        for (int c = 0; c < CT; ++c) {
            accu[c] = (f32x4){0.f, 0.f, 0.f, 0.f};
            accv[c] = (f32x4){0.f, 0.f, 0.f, 0.f};
        }
#pragma unroll
        for (int c = 0; c < CT; ++c)
#pragma unroll
            for (int ch = 0; ch < CH; ++ch) {
                accu[c] = __builtin_amdgcn_mfma_f32_16x16x32_bf16(au[ch], bu[c][ch], accu[c], 0, 0, 0);
                accv[c] = __builtin_amdgcn_mfma_f32_16x16x32_bf16(av[ch], bv[c][ch], accv[c], 0, 0, 0);
            }

        float res[CT][4];
        float sq[4] = {0.f, 0.f, 0.f, 0.f};
#pragma unroll
        for (int c = 0; c < CT; ++c) {
            float bb1 = b1[c * 16 + m];
            float bb2 = b2[c * 16 + m];
#pragma unroll
            for (int i = 0; i < 4; ++i) {
                float o1 = accu[c][i] + bb1;
                float o2 = accv[c][i] + bb2;
                float r1 = (o1 >= 0.f) ? o1 : 0.01f * o1;
                float r2 = (o2 >= 0.f) ? o2 : 0.01f * o2;
                float rr = r1 + r2;
                res[c][i] = rr;
                sq[i] = fmaf(rr, rr, sq[i]);
            }
        }
#pragma unroll
        for (int mask = 1; mask < 16; mask <<= 1)
#pragma unroll
            for (int i = 0; i < 4; ++i)
                sq[i] += __shfl_xor(sq[i], mask, 64);

#pragma unroll
        for (int i = 0; i < 4; ++i) {
            int row = row0 + q * 4 + i;
            float inv = 1.f / fmaxf(sqrtf(sq[i]), 1e-12f);
#pragma unroll
            for (int c = 0; c < CT; ++c) {
                int col = c * 16 + m;
                out_buf[(size_t)row * OUT_STRIDE + out_col + col] = res[c][i] * inv;
                if (ho_p0) {
                    ushort hb = f2bf(res[c][i]);
                    if (col < 32) ho_p0[(size_t)row * 32 + col] = hb;
                    else          ho_p1[(size_t)row * 32 + (col - 32)] = hb;
                }
            }
        }
    }
}

// ---------------------------------------------------------------------------
extern "C" void kernel_launch(void* const* d_in, const int* in_sizes, int n_in,
                              void* d_out, int out_size, void* d_ws, size_t ws_size,
                              hipStream_t stream) {
    const float* ent  = (const float*)d_in[0];
    const float* rel  = (const float*)d_in[1];
    const float* W_R  = (const float*)d_in[2];
    const float* W1_0 = (const float*)d_in[3];
    const float* b1_0 = (const float*)d_in[4];
    const float* W2_0 = (const float*)d_in[5];
    const float* b2_0 = (const float*)d_in[6];
    const float* W1_1 = (const float*)d_in[7];
    const float* b1_1 = (const float*)d_in[8];
    const float* W2_1 = (const float*)d_in[9];
    const float* b2_1 = (const float*)d_in[10];
    const float* W1_2 = (const float*)d_in[11];
    const float* b1_2 = (const float*)d_in[12];
    const float* W2_2 = (const float*)d_in[13];
    const float* b2_2 = (const float*)d_in[14];
    const int*   src   = (const int*)d_in[15];
    const int*   dst   = (const int*)d_in[16];
    const int*   etype = (const int*)d_in[17];
    float* out = (float*)d_out;

    // workspace layout
    char* w = (char*)d_ws;
    float*  att_csr = (float*)w;  w += (size_t)N_EDGE * 4;              // 4 MB
    int*    src_csr = (int*)w;    w += (size_t)N_EDGE * 4;              // 4 MB
    int*    counts  = (int*)w;    w += (size_t)(N_ENT + 64) * 4;
    int*    row_ptr = (int*)w;    w += (size_t)(N_ENT + 64) * 4;
    int*    cursor  = (int*)w;    w += (size_t)(N_ENT + 64) * 4;
    int*    excl    = (int*)w;    w += (size_t)(N_ENT + 64) * 4;
    int*    bsum    = (int*)w;    w += 256 * 4;
    int*    boff    = (int*)w;    w += 256 * 4;
    ushort* ent_bf  = (ushort*)w; w += (size_t)N_ENT * 64 * 2;          // 6.4 MB
    ushort* ent_p0  = (ushort*)w; w += (size_t)N_ENT * 32 * 2;          // 3.2 MB
    ushort* ent_p1  = (ushort*)w; w += (size_t)N_ENT * 32 * 2;          // 3.2 MB
    ushort* h1_p0   = (ushort*)w; w += (size_t)N_ENT * 32 * 2;          // 3.2 MB
    ushort* h1_p1   = (ushort*)w; w += (size_t)N_ENT * 32 * 2;          // 3.2 MB
    ushort* h2      = (ushort*)w; w += (size_t)N_ENT * 32 * 2;          // 3.2 MB
    float*  N_h     = (float*)w;  w += (size_t)N_ENT * 64 * 4;          // 12.8 MB
    __hip_bfloat16* Z = (__hip_bfloat16*)w;                             // 102 MB
    (void)ws_size;

    hipMemsetAsync(counts, 0, (size_t)N_ENT * 4, stream);
    hipMemsetAsync(cursor, 0, (size_t)N_ENT * 4, stream);

    const int nb = (N_ENT + 255) / 256;   // 196 scan blocks

    ent_prep_kernel<<<(N_ENT * DIM + 255) / 256, 256, 0, stream>>>(
        ent, ent_bf, ent_p0, ent_p1, out, N_ENT * DIM);
    hist_kernel<<<(N_EDGE + 255) / 256, 256, 0, stream>>>(dst, counts, N_EDGE);
    scan1_kernel<<<nb, 256, 0, stream>>>(counts, excl, bsum, N_ENT);
    scan2_kernel<<<1, 256, 0, stream>>>(bsum, boff, row_ptr, nb, N_ENT);
    scan3_kernel<<<nb, 256, 0, stream>>>(excl, boff, row_ptr, N_ENT);

    gz_mfma_kernel<<<dim3(64, N_RELS), 256, 0, stream>>>(ent_bf, W_R, rel, Z);
    att_dot_kernel<<<((N_EDGE + 7) / 8 * 64 + 255) / 256, 256, 0, stream>>>(
        ent_bf, Z, src, dst, etype, row_ptr, cursor, att_csr, src_csr, N_EDGE);

    softmax_kernel<<<(N_ENT + 3) / 4, 256, 0, stream>>>(row_ptr, att_csr, N_ENT);

    const int aggGrid = (N_ENT + 3) / 4;
    const int mlpGrid = 782;

    // ---- layer 0: D_IN=64 (ent planes) -> D_OUT=64 (h1 planes) ----
    agg_kernel<<<aggGrid, 256, 0, stream>>>(ent_p0, att_csr, src_csr, row_ptr, N_h, 64, 0,  N_ENT);
    agg_kernel<<<aggGrid, 256, 0, stream>>>(ent_p1, att_csr, src_csr, row_ptr, N_h, 64, 32, N_ENT);
    mlp_mfma_kernel<64, 64><<<mlpGrid, 256, 0, stream>>>(
        ent_p0, ent_p1, N_h, W1_0, b1_0, W2_0, b2_0, h1_p0, h1_p1, out, 64);

    // ---- layer 1: D_IN=64 (h1 planes) -> D_OUT=32 (h2 flat) ----
    agg_kernel<<<aggGrid, 256, 0, stream>>>(h1_p0, att_csr, src_csr, row_ptr, N_h, 64, 0,  N_ENT);
    agg_kernel<<<aggGrid, 256, 0, stream>>>(h1_p1, att_csr, src_csr, row_ptr, N_h, 64, 32, N_ENT);
    mlp_mfma_kernel<64, 32><<<mlpGrid, 256, 0, stream>>>(
        h1_p0, h1_p1, N_h, W1_1, b1_1, W2_1, b2_1, h2, nullptr, out, 128);

    // ---- layer 2: D_IN=32 (h2 flat) -> D_OUT=16 ----
    agg_kernel<<<aggGrid, 256, 0, stream>>>(h2, att_csr, src_csr, row_ptr, N_h, 32, 0, N_ENT);
    mlp_mfma_kernel<32, 16><<<mlpGrid, 256, 0, stream>>>(
        h2, nullptr, N_h, W1_2, b1_2, W2_2, b2_2, nullptr, nullptr, out, 160);
}

// Round 9
// 431.029 us; speedup vs baseline: 1.6220x; 1.0553x over previous
//
#include <hip/hip_runtime.h>
#include <hip/hip_bf16.h>
#include <cmath>

#define N_ENT  50000
#define N_RELS 16
#define N_EDGE 1000000
#define DIM    64
#define OUT_STRIDE 176

typedef float f32x4 __attribute__((ext_vector_type(4)));
typedef short s16x8 __attribute__((ext_vector_type(8)));

__device__ inline void bf16x8_unpack(uint4 u, float* f) {
    f[0] = __uint_as_float((u.x & 0xffffu) << 16);
    f[1] = __uint_as_float(u.x & 0xffff0000u);
    f[2] = __uint_as_float((u.y & 0xffffu) << 16);
    f[3] = __uint_as_float(u.y & 0xffff0000u);
    f[4] = __uint_as_float((u.z & 0xffffu) << 16);
    f[5] = __uint_as_float(u.z & 0xffff0000u);
    f[6] = __uint_as_float((u.w & 0xffffu) << 16);
    f[7] = __uint_as_float(u.w & 0xffff0000u);
}

__device__ inline ushort f2bf(float x) {
    __hip_bfloat16 b = __float2bfloat16(x);
    return *(ushort*)&b;
}

// ---------------------------------------------------------------------------
// K0: fused prep — ent fp32 -> bf16 flat + two planes + out[:,0:64] copy,
// and dst histogram (hides the 1M atomic-incs under the 32 MB streaming).
// ---------------------------------------------------------------------------
__global__ __launch_bounds__(256) void prep_hist_kernel(
        const float* __restrict__ ent,
        ushort* __restrict__ ent_bf,
        ushort* __restrict__ p0, ushort* __restrict__ p1,
        float* __restrict__ out,
        const int* __restrict__ dst, int* __restrict__ counts) {
    int i = blockIdx.x * blockDim.x + threadIdx.x;
    if (i < N_ENT * DIM) {
        float v = ent[i];
        ushort b = f2bf(v);
        int n = i >> 6, c = i & 63;
        ent_bf[i] = b;
        if (c < 32) p0[n * 32 + c] = b;
        else        p1[n * 32 + (c - 32)] = b;
        out[(size_t)n * OUT_STRIDE + c] = v;
    }
    if (i < N_EDGE) atomicAdd(&counts[dst[i]], 1);
}

// ---------------------------------------------------------------------------
// K2: 3-phase multi-block exclusive scan counts -> row_ptr
// ---------------------------------------------------------------------------
__global__ __launch_bounds__(256) void scan1_kernel(
        const int* __restrict__ counts, int* __restrict__ excl,
        int* __restrict__ bsum, int n) {
    __shared__ int sh[256];
    int t = threadIdx.x;
    int i = blockIdx.x * 256 + t;
    int c = (i < n) ? counts[i] : 0;
    sh[t] = c;
    __syncthreads();
    for (int off = 1; off < 256; off <<= 1) {
        int v = (t >= off) ? sh[t - off] : 0;
        __syncthreads();
        sh[t] += v;
        __syncthreads();
    }
    if (i < n) excl[i] = sh[t] - c;
    if (t == 255) bsum[blockIdx.x] = sh[255];
}

__global__ __launch_bounds__(256) void scan2_kernel(
        const int* __restrict__ bsum, int* __restrict__ boff,
        int* __restrict__ row_ptr, int nb, int n) {
    __shared__ int sh[256];
    int t = threadIdx.x;
    int v = (t < nb) ? bsum[t] : 0;
    sh[t] = v;
    __syncthreads();
    for (int off = 1; off < 256; off <<= 1) {
        int x = (t >= off) ? sh[t - off] : 0;
        __syncthreads();
        sh[t] += x;
        __syncthreads();
    }
    if (t < nb) boff[t] = sh[t] - v;
    if (t == nb - 1) row_ptr[n] = sh[t];
}

__global__ __launch_bounds__(256) void scan3_kernel(
        const int* __restrict__ excl, const int* __restrict__ boff,
        int* __restrict__ row_ptr, int n) {
    int i = blockIdx.x * blockDim.x + threadIdx.x;
    if (i < n) row_ptr[i] = excl[i] + boff[i >> 8];
}

// ---------------------------------------------------------------------------
// K3a: fused G->Z kernel:  Z_r = tanh(ent @ W_r + rel_r) @ W_r^T  (bf16 out)
// ---------------------------------------------------------------------------
__global__ __launch_bounds__(256) void gz_mfma_kernel(
        const ushort* __restrict__ ent_bf,
        const float*  __restrict__ W_R,
        const float*  __restrict__ rel,
        __hip_bfloat16* __restrict__ Z) {
    __shared__ float lds[4][16 * 68 + 16];
    int lane = threadIdx.x & 63;
    int wv   = threadIdx.x >> 6;
    int m    = lane & 15;
    int q    = lane >> 4;
    int r    = blockIdx.y;
    int wid  = blockIdx.x * 4 + wv;
    int nw   = gridDim.x * 4;

    const float* Wr = W_R + (size_t)r * DIM * DIM;
    s16x8 b1[4][2], b2[4][2];
#pragma unroll
    for (int c = 0; c < 4; ++c)
#pragma unroll
        for (int ch = 0; ch < 2; ++ch)
#pragma unroll
            for (int j = 0; j < 8; ++j) {
                b1[c][ch][j] = (short)f2bf(Wr[(ch * 32 + q * 8 + j) * DIM + c * 16 + m]);
                b2[c][ch][j] = (short)f2bf(Wr[(c * 16 + m) * DIM + ch * 32 + q * 8 + j]);
            }
    float relv[4];
#pragma unroll
    for (int c = 0; c < 4; ++c) relv[c] = rel[r * DIM + c * 16 + m];

    float* myLds = lds[wv];
    const int ntiles = N_ENT / 16;

    for (int t = wid; t < ntiles; t += nw) {
        int row0 = t * 16;
        const s16x8* arow = (const s16x8*)(ent_bf + (size_t)(row0 + m) * DIM);
        s16x8 a0 = arow[q];
        s16x8 a1 = arow[4 + q];
        f32x4 acc[4];
#pragma unroll
        for (int c = 0; c < 4; ++c) acc[c] = (f32x4){0.f, 0.f, 0.f, 0.f};
#pragma unroll
        for (int c = 0; c < 4; ++c) {
            acc[c] = __builtin_amdgcn_mfma_f32_16x16x32_bf16(a0, b1[c][0], acc[c], 0, 0, 0);
            acc[c] = __builtin_amdgcn_mfma_f32_16x16x32_bf16(a1, b1[c][1], acc[c], 0, 0, 0);
        }
#pragma unroll
        for (int c = 0; c < 4; ++c)
#pragma unroll
            for (int i = 0; i < 4; ++i) {
                float x = acc[c][i] + relv[c];
                float g = 1.f - 2.f / (__expf(2.f * x) + 1.f);
                myLds[(q * 4 + i) * 68 + c * 16 + m] = g;
            }
        s16x8 a2[2];
#pragma unroll
        for (int ch = 0; ch < 2; ++ch)
#pragma unroll
            for (int j = 0; j < 8; ++j)
                a2[ch][j] = (short)f2bf(myLds[m * 68 + ch * 32 + q * 8 + j]);

        f32x4 zacc[4];
#pragma unroll
        for (int c = 0; c < 4; ++c) zacc[c] = (f32x4){0.f, 0.f, 0.f, 0.f};
#pragma unroll
        for (int c = 0; c < 4; ++c) {
            zacc[c] = __builtin_amdgcn_mfma_f32_16x16x32_bf16(a2[0], b2[c][0], zacc[c], 0, 0, 0);
            zacc[c] = __builtin_amdgcn_mfma_f32_16x16x32_bf16(a2[1], b2[c][1], zacc[c], 0, 0, 0);
        }
        __hip_bfloat16* zrow = Z + ((size_t)r * N_ENT + row0) * DIM;
#pragma unroll
        for (int c = 0; c < 4; ++c)
#pragma unroll
            for (int i = 0; i < 4; ++i)
                zrow[(q * 4 + i) * DIM + c * 16 + m] = __float2bfloat16(zacc[c][i]);
    }
}

// ---------------------------------------------------------------------------
// K3b: per-edge logit = dot(ent_bf[s], Z[r][d]). 8 edges/wave.
// CSR fill: ONE packed 8-B scattered store per edge {att_bits, src}.
// ---------------------------------------------------------------------------
__global__ __launch_bounds__(256) void att_dot_kernel(
        const ushort* __restrict__ ent_bf,
        const __hip_bfloat16* __restrict__ Z,
        const int* __restrict__ src,
        const int* __restrict__ dst,
        const int* __restrict__ etype,
        const int* __restrict__ row_ptr,
        int* __restrict__ cursor,
        uint2* __restrict__ es_csr,
        int n_edge) {
    int tid  = blockIdx.x * blockDim.x + threadIdx.x;
    int lane = threadIdx.x & 63;
    int sub  = lane >> 3;
    int q    = lane & 7;
    int e    = (tid >> 6) * 8 + sub;
    if (e >= n_edge) return;

    int s = src[e];
    int d = dst[e];
    int r = etype[e];

    uint4 uz = *(const uint4*)(Z + ((size_t)r * N_ENT + d) * DIM + q * 8);
    uint4 ue = *(const uint4*)(ent_bf + (size_t)s * DIM + q * 8);

    float zv[8], ev[8];
    bf16x8_unpack(uz, zv);
    bf16x8_unpack(ue, ev);

    float prod = 0.f;
#pragma unroll
    for (int j = 0; j < 8; ++j) prod = fmaf(ev[j], zv[j], prod);
    prod += __shfl_xor(prod, 1, 64);
    prod += __shfl_xor(prod, 2, 64);
    prod += __shfl_xor(prod, 4, 64);

    if (q == 0) {
        int pos = row_ptr[d] + atomicAdd(&cursor[d], 1);
        es_csr[pos] = make_uint2(__float_as_uint(prod), (unsigned)s);
    }
}

// ---------------------------------------------------------------------------
// K4: edge softmax per dst node, in place on the packed array's .x field
// ---------------------------------------------------------------------------
__global__ __launch_bounds__(256) void softmax_kernel(
        const int* __restrict__ row_ptr, uint2* __restrict__ es_csr, int n_node) {
    int wid  = (blockIdx.x * blockDim.x + threadIdx.x) >> 6;
    int lane = threadIdx.x & 63;
    if (wid >= n_node) return;
    int start = row_ptr[wid], end = row_ptr[wid + 1];

    float m = -INFINITY;
    for (int i = start + lane; i < end; i += 64)
        m = fmaxf(m, __uint_as_float(es_csr[i].x));
#pragma unroll
    for (int off = 32; off > 0; off >>= 1)
        m = fmaxf(m, __shfl_xor(m, off, 64));

    float ssum = 0.f;
    for (int i = start + lane; i < end; i += 64) {
        float e = expf(__uint_as_float(es_csr[i].x) - m);
        es_csr[i].x = __float_as_uint(e);
        ssum += e;
    }
#pragma unroll
    for (int off = 32; off > 0; off >>= 1)
        ssum += __shfl_xor(ssum, off, 64);

    if (end > start) {
        float inv = 1.0f / ssum;
        for (int i = start + lane; i < end; i += 64) {
            float a = __uint_as_float(es_csr[i].x) * inv;
            es_csr[i].x = __float_as_uint(a);
        }
    }
}

// ---------------------------------------------------------------------------
// K6a: aggregation over one 32-dim plane (L2-resident 3.2 MB table).
// ---------------------------------------------------------------------------
__global__ __launch_bounds__(256) void agg_kernel(
        const ushort* __restrict__ plane,    // [N][32] bf16
        const uint2* __restrict__ es_csr,
        const int* __restrict__ row_ptr,
        float* __restrict__ N_h, int stride, int off, int n_node) {
    int wid  = (blockIdx.x * blockDim.x + threadIdx.x) >> 6;
    int lane = threadIdx.x & 63;
    if (wid >= n_node) return;
    int q   = lane & 3;
    int sub = lane >> 2;

    int start = row_ptr[wid], end = row_ptr[wid + 1];
    float acc[8];
#pragma unroll
    for (int j = 0; j < 8; ++j) acc[j] = 0.f;

    for (int p = start + sub; p < end; p += 16) {
        uint2 es = es_csr[p];
        float av = __uint_as_float(es.x);
        int   si = (int)es.y;
        uint4 u  = *(const uint4*)(plane + (size_t)si * 32 + q * 8);
        float g[8];
        bf16x8_unpack(u, g);
#pragma unroll
        for (int j = 0; j < 8; ++j) acc[j] = fmaf(av, g[j], acc[j]);
    }
#pragma unroll
    for (int mask = 4; mask < 64; mask <<= 1)
#pragma unroll
        for (int j = 0; j < 8; ++j)
            acc[j] += __shfl_xor(acc[j], mask, 64);

    if (sub == 0) {
        float* dstp = N_h + (size_t)wid * stride + off + q * 8;
        *(float4*)(dstp)     = (float4){acc[0], acc[1], acc[2], acc[3]};
        *(float4*)(dstp + 4) = (float4){acc[4], acc[5], acc[6], acc[7]};
    }
}

// ---------------------------------------------------------------------------
// K6b: dense bi-interaction MLP via MFMA, fused bias/leaky/l2-norm epilogue.
// ---------------------------------------------------------------------------
template <int D_IN, int D_OUT>
__global__ __launch_bounds__(256) void mlp_mfma_kernel(
        const ushort* __restrict__ h_p0,
        const ushort* __restrict__ h_p1,
        const float* __restrict__ N_h,
        const float* __restrict__ W1, const float* __restrict__ b1,
        const float* __restrict__ W2, const float* __restrict__ b2,
        ushort* __restrict__ ho_p0,
        ushort* __restrict__ ho_p1,
        float* __restrict__ out_buf, int out_col) {
    constexpr int CH = D_IN / 32;
    constexpr int CT = D_OUT / 16;

    int lane = threadIdx.x & 63;
    int m    = lane & 15;
    int q    = lane >> 4;
    int wid  = blockIdx.x * (blockDim.x >> 6) + (threadIdx.x >> 6);
    int nw   = gridDim.x * (blockDim.x >> 6);

    s16x8 bu[CT][CH], bv[CT][CH];
#pragma unroll
    for (int c = 0; c < CT; ++c)
#pragma unroll
        for (int ch = 0; ch < CH; ++ch)
#pragma unroll
            for (int j = 0; j < 8; ++j) {
                int k = ch * 32 + q * 8 + j;
                bu[c][ch][j] = (short)f2bf(W1[k * D_OUT + c * 16 + m]);
                bv[c][ch][j] = (short)f2bf(W2[k * D_OUT + c * 16 + m]);
            }

    const int ntiles = N_ENT / 16;
    for (int t = wid; t < ntiles; t += nw) {
        int row0 = t * 16;
        s16x8 au[CH], av[CH];
#pragma unroll
        for (int ch = 0; ch < CH; ++ch) {
            const ushort* hp = (ch == 0) ? h_p0 : h_p1;
            uint4 hu = *(const uint4*)(hp + (size_t)(row0 + m) * 32 + q * 8);
            float hv8[8];
            bf16x8_unpack(hu, hv8);
            const float4* np = (const float4*)(N_h + (size_t)(row0 + m) * D_IN + ch * 32 + q * 8);
            float4 na = np[0], nb = np[1];
            float nv[8] = {na.x, na.y, na.z, na.w, nb.x, nb.y, nb.z, nb.w};
#pragma unroll
            for (int j = 0; j < 8; ++j) {
                au[ch][j] = (short)f2bf(hv8[j] + nv[j]);
                av[ch][j] = (short)f2bf(hv8[j] * nv[j]);
            }
        }

        f32x4 accu[CT], accv[CT];
#pragma unroll
        for (int c = 0; c < CT; ++c) {
            accu[c] = (f32x4){0.f, 0.f, 0.f, 0.f};
            accv[c] = (f32x4){0.f, 0.f, 0.f, 0.f};
        }
#pragma unroll
        for (int c = 0; c < CT; ++c)
#pragma unroll
            for (int ch = 0; ch < CH; ++ch) {
                accu[c] = __builtin_amdgcn_mfma_f32_16x16x32_bf16(au[ch], bu[c][ch], accu[c], 0, 0, 0);
                accv[c] = __builtin_amdgcn_mfma_f32_16x16x32_bf16(av[ch], bv[c][ch], accv[c], 0, 0, 0);
            }

        float res[CT][4];
        float sq[4] = {0.f, 0.f, 0.f, 0.f};
#pragma unroll
        for (int c = 0; c < CT; ++c) {
            float bb1 = b1[c * 16 + m];
            float bb2 = b2[c * 16 + m];
#pragma unroll
            for (int i = 0; i < 4; ++i) {
                float o1 = accu[c][i] + bb1;
                float o2 = accv[c][i] + bb2;
                float r1 = (o1 >= 0.f) ? o1 : 0.01f * o1;
                float r2 = (o2 >= 0.f) ? o2 : 0.01f * o2;
                float rr = r1 + r2;
                res[c][i] = rr;
                sq[i] = fmaf(rr, rr, sq[i]);
            }
        }
#pragma unroll
        for (int mask = 1; mask < 16; mask <<= 1)
#pragma unroll
            for (int i = 0; i < 4; ++i)
                sq[i] += __shfl_xor(sq[i], mask, 64);

#pragma unroll
        for (int i = 0; i < 4; ++i) {
            int row = row0 + q * 4 + i;
            float inv = 1.f / fmaxf(sqrtf(sq[i]), 1e-12f);
#pragma unroll
            for (int c = 0; c < CT; ++c) {
                int col = c * 16 + m;
                out_buf[(size_t)row * OUT_STRIDE + out_col + col] = res[c][i] * inv;
                if (ho_p0) {
                    ushort hb = f2bf(res[c][i]);
                    if (col < 32) ho_p0[(size_t)row * 32 + col] = hb;
                    else          ho_p1[(size_t)row * 32 + (col - 32)] = hb;
                }
            }
        }
    }
}

// ---------------------------------------------------------------------------
extern "C" void kernel_launch(void* const* d_in, const int* in_sizes, int n_in,
                              void* d_out, int out_size, void* d_ws, size_t ws_size,
                              hipStream_t stream) {
    const float* ent  = (const float*)d_in[0];
    const float* rel  = (const float*)d_in[1];
    const float* W_R  = (const float*)d_in[2];
    const float* W1_0 = (const float*)d_in[3];
    const float* b1_0 = (const float*)d_in[4];
    const float* W2_0 = (const float*)d_in[5];
    const float* b2_0 = (const float*)d_in[6];
    const float* W1_1 = (const float*)d_in[7];
    const float* b1_1 = (const float*)d_in[8];
    const float* W2_1 = (const float*)d_in[9];
    const float* b2_1 = (const float*)d_in[10];
    const float* W1_2 = (const float*)d_in[11];
    const float* b1_2 = (const float*)d_in[12];
    const float* W2_2 = (const float*)d_in[13];
    const float* b2_2 = (const float*)d_in[14];
    const int*   src   = (const int*)d_in[15];
    const int*   dst   = (const int*)d_in[16];
    const int*   etype = (const int*)d_in[17];
    float* out = (float*)d_out;

    // workspace layout
    char* w = (char*)d_ws;
    uint2*  es_csr  = (uint2*)w;  w += (size_t)N_EDGE * 8;              // 8 MB packed
    int*    counts  = (int*)w;    w += (size_t)(N_ENT + 64) * 4;
    int*    row_ptr = (int*)w;    w += (size_t)(N_ENT + 64) * 4;
    int*    cursor  = (int*)w;    w += (size_t)(N_ENT + 64) * 4;
    int*    excl    = (int*)w;    w += (size_t)(N_ENT + 64) * 4;
    int*    bsum    = (int*)w;    w += 256 * 4;
    int*    boff    = (int*)w;    w += 256 * 4;
    ushort* ent_bf  = (ushort*)w; w += (size_t)N_ENT * 64 * 2;          // 6.4 MB
    ushort* ent_p0  = (ushort*)w; w += (size_t)N_ENT * 32 * 2;          // 3.2 MB
    ushort* ent_p1  = (ushort*)w; w += (size_t)N_ENT * 32 * 2;          // 3.2 MB
    ushort* h1_p0   = (ushort*)w; w += (size_t)N_ENT * 32 * 2;          // 3.2 MB
    ushort* h1_p1   = (ushort*)w; w += (size_t)N_ENT * 32 * 2;          // 3.2 MB
    ushort* h2      = (ushort*)w; w += (size_t)N_ENT * 32 * 2;          // 3.2 MB
    float*  N_h     = (float*)w;  w += (size_t)N_ENT * 64 * 4;          // 12.8 MB
    __hip_bfloat16* Z = (__hip_bfloat16*)w;                             // 102 MB
    (void)ws_size;

    hipMemsetAsync(counts, 0, (size_t)N_ENT * 4, stream);
    hipMemsetAsync(cursor, 0, (size_t)N_ENT * 4, stream);

    const int nb = (N_ENT + 255) / 256;   // 196 scan blocks

    prep_hist_kernel<<<(N_ENT * DIM + 255) / 256, 256, 0, stream>>>(
        ent, ent_bf, ent_p0, ent_p1, out, dst, counts);
    scan1_kernel<<<nb, 256, 0, stream>>>(counts, excl, bsum, N_ENT);
    scan2_kernel<<<1, 256, 0, stream>>>(bsum, boff, row_ptr, nb, N_ENT);
    scan3_kernel<<<nb, 256, 0, stream>>>(excl, boff, row_ptr, N_ENT);

    gz_mfma_kernel<<<dim3(64, N_RELS), 256, 0, stream>>>(ent_bf, W_R, rel, Z);
    att_dot_kernel<<<((N_EDGE + 7) / 8 * 64 + 255) / 256, 256, 0, stream>>>(
        ent_bf, Z, src, dst, etype, row_ptr, cursor, es_csr, N_EDGE);

    softmax_kernel<<<(N_ENT + 3) / 4, 256, 0, stream>>>(row_ptr, es_csr, N_ENT);

    const int aggGrid = (N_ENT + 3) / 4;
    const int mlpGrid = 782;

    // ---- layer 0: D_IN=64 (ent planes) -> D_OUT=64 (h1 planes) ----
    agg_kernel<<<aggGrid, 256, 0, stream>>>(ent_p0, es_csr, row_ptr, N_h, 64, 0,  N_ENT);
    agg_kernel<<<aggGrid, 256, 0, stream>>>(ent_p1, es_csr, row_ptr, N_h, 64, 32, N_ENT);
    mlp_mfma_kernel<64, 64><<<mlpGrid, 256, 0, stream>>>(
        ent_p0, ent_p1, N_h, W1_0, b1_0, W2_0, b2_0, h1_p0, h1_p1, out, 64);

    // ---- layer 1: D_IN=64 (h1 planes) -> D_OUT=32 (h2 flat) ----
    agg_kernel<<<aggGrid, 256, 0, stream>>>(h1_p0, es_csr, row_ptr, N_h, 64, 0,  N_ENT);
    agg_kernel<<<aggGrid, 256, 0, stream>>>(h1_p1, es_csr, row_ptr, N_h, 64, 32, N_ENT);
    mlp_mfma_kernel<64, 32><<<mlpGrid, 256, 0, stream>>>(
        h1_p0, h1_p1, N_h, W1_1, b1_1, W2_1, b2_1, h2, nullptr, out, 128);

    // ---- layer 2: D_IN=32 (h2 flat) -> D_OUT=16 ----
    agg_kernel<<<aggGrid, 256, 0, stream>>>(h2, es_csr, row_ptr, N_h, 32, 0, N_ENT);
    mlp_mfma_kernel<32, 16><<<mlpGrid, 256, 0, stream>>>(
        h2, nullptr, N_h, W1_2, b1_2, W2_2, b2_2, nullptr, nullptr, out, 160);
}